// Round 1
// baseline (3977.009 us; speedup 1.0000x reference)
//
#include <hip/hip_runtime.h>

// DepthFlowProjection (DAIN, fillhole=0) forward.
// flow:  [B,2,H,W] f32, depth: [B,1,H,W] f32  -> out: [B,2,H,W] f32
//
// Pass 1: zero accumulators (count in d_ws, out_x/out_y in d_out).
// Pass 2: scatter d, -fx*d, -fy*d onto 4 corners around (x+fx, y+fy) via atomics.
// Pass 3: divide by count (or 1 where count==0).

__global__ void dfp_scatter(const float* __restrict__ flow,
                            const float* __restrict__ depth,
                            float* __restrict__ out,    // [B,2,H,W] accumulators
                            float* __restrict__ count,  // [B,H,W]
                            int B, int H, int W) {
    const int HWl = H * W;
    const long total = (long)B * HWl;
    long idx = (long)blockIdx.x * blockDim.x + threadIdx.x;
    if (idx >= total) return;

    int b = (int)(idx / HWl);
    int p = (int)(idx - (long)b * HWl);
    int y = p / W;
    int x = p - y * W;

    const float* f = flow + (size_t)b * 2 * HWl;
    float fx = f[p];
    float fy = f[HWl + p];
    float d  = depth[idx];

    float x2 = (float)x + fx;
    float y2 = (float)y + fy;

    // invalid pixels contribute d*0 = 0 to every corner -> no-op, skip
    if (!(x2 >= 0.0f && y2 >= 0.0f && x2 <= (float)(W - 1) && y2 <= (float)(H - 1)))
        return;

    int ixL = (int)floorf(x2);
    int iyT = (int)floorf(y2);
    // clip (matches reference; valid range already guarantees >= 0)
    ixL = min(max(ixL, 0), W - 1);
    iyT = min(max(iyT, 0), H - 1);
    int ixR = min(ixL + 1, W - 1);
    int iyB = min(iyT + 1, H - 1);

    float vx = -fx * d;
    float vy = -fy * d;

    float* cnt_b  = count + (size_t)b * HWl;
    float* outx_b = out + (size_t)b * 2 * HWl;
    float* outy_b = outx_b + HWl;

    int o00 = iyT * W + ixL;
    int o01 = iyT * W + ixR;
    int o10 = iyB * W + ixL;
    int o11 = iyB * W + ixR;

    // Reference always adds all 4 corners, even when duplicated at borders.
    atomicAdd(&cnt_b[o00], d);
    atomicAdd(&cnt_b[o01], d);
    atomicAdd(&cnt_b[o10], d);
    atomicAdd(&cnt_b[o11], d);

    atomicAdd(&outx_b[o00], vx);
    atomicAdd(&outx_b[o01], vx);
    atomicAdd(&outx_b[o10], vx);
    atomicAdd(&outx_b[o11], vx);

    atomicAdd(&outy_b[o00], vy);
    atomicAdd(&outy_b[o01], vy);
    atomicAdd(&outy_b[o10], vy);
    atomicAdd(&outy_b[o11], vy);
}

__global__ void dfp_normalize(float* __restrict__ out,
                              const float* __restrict__ count,
                              int B, int HWl) {
    const long total = (long)B * HWl;
    long idx = (long)blockIdx.x * blockDim.x + threadIdx.x;
    if (idx >= total) return;

    int b = (int)(idx / HWl);
    int p = (int)(idx - (long)b * HWl);

    float c = count[idx];
    float denom = (c > 0.0f) ? c : 1.0f;

    size_t o = (size_t)b * 2 * HWl + p;
    out[o]       = out[o] / denom;
    out[o + HWl] = out[o + HWl] / denom;
}

extern "C" void kernel_launch(void* const* d_in, const int* in_sizes, int n_in,
                              void* d_out, int out_size, void* d_ws, size_t ws_size,
                              hipStream_t stream) {
    const float* flow  = (const float*)d_in[0];
    const float* depth = (const float*)d_in[1];
    float* out = (float*)d_out;
    float* cnt = (float*)d_ws;

    // Shapes per setup_inputs(): B=4, H=1080, W=1920
    const int H = 1080, W = 1920;
    const int HWl = H * W;
    const int B = in_sizes[1] / HWl;  // depth has B*H*W elements

    const long total = (long)B * HWl;

    hipMemsetAsync(d_out, 0, (size_t)total * 2 * sizeof(float), stream);
    hipMemsetAsync(d_ws, 0, (size_t)total * sizeof(float), stream);

    const int threads = 256;
    const int blocks = (int)((total + threads - 1) / threads);

    dfp_scatter<<<blocks, threads, 0, stream>>>(flow, depth, out, cnt, B, H, W);
    dfp_normalize<<<blocks, threads, 0, stream>>>(out, cnt, B, HWl);
}